// Round 6
// baseline (177.404 us; speedup 1.0000x reference)
//
#include <hip/hip_runtime.h>
#include <hip/hip_bf16.h>

// Problem constants
// B=2, T=2048, C=1024, H=16, HD=64, 3C=3072, M=B*T=4096

typedef __attribute__((ext_vector_type(8))) short short8;
typedef __attribute__((ext_vector_type(4))) float floatx4;

__device__ __forceinline__ unsigned short f2bf(float f) {
    union { float f; unsigned int u; } v; v.f = f;
    unsigned int r = v.u + 0x7FFFu + ((v.u >> 16) & 1u);
    return (unsigned short)(r >> 16);
}

// pack 2 fp32 -> 2 bf16 (round-half-up) in one v_perm_b32; result mem order: a,b
__device__ __forceinline__ unsigned int pk2bf(float a, float b) {
    union { float f; unsigned int u; } ua, ub;
    ua.f = a; ub.f = b;
    return __builtin_amdgcn_perm(ub.u + 0x8000u, ua.u + 0x8000u, 0x07060302u);
}

// 2 fp32 -> packed bf16x2 (RNE) in one instruction; mem order: a (low), b (high)
__device__ __forceinline__ unsigned int cvtpk(float a, float b) {
    unsigned int r;
    asm("v_cvt_pk_bf16_f32 %0, %1, %2" : "=v"(r) : "v"(a), "v"(b));
    return r;
}

__device__ __forceinline__ void gld16(const void* g, void* l) {
    __builtin_amdgcn_global_load_lds(
        (const __attribute__((address_space(1))) unsigned int*)g,
        (__attribute__((address_space(3))) unsigned int*)l, 16, 0, 0);
}

// ---------------- fused prep: cast x, transpose w_attn/w_proj, rope table --
__device__ __forceinline__ void transpose_body(
    const float* __restrict__ in, unsigned short* __restrict__ out,
    int R, int NC, int bx, int by, int tid,
    unsigned short (*tile)[68]) {
    int r0 = by * 64, c0 = bx * 64;
    // vectorized load phase: float4 per thread, 4 passes of 16 rows
    int c4 = (tid & 15) * 4, rr = tid >> 4;
#pragma unroll
    for (int i = 0; i < 4; i++) {
        int row = rr + i * 16;
        float4 v = *(const float4*)&in[(size_t)(r0 + row) * NC + c0 + c4];
        ushort4 o;
        o.x = f2bf(v.x); o.y = f2bf(v.y); o.z = f2bf(v.z); o.w = f2bf(v.w);
        *(ushort4*)&tile[row][c4] = o;
    }
    __syncthreads();
    int col = tid & 63, rr2 = tid >> 6;
#pragma unroll
    for (int i = 0; i < 16; i++) {
        int orow = rr2 + i * 4;
        out[(size_t)(c0 + orow) * R + r0 + col] = tile[col][orow];
    }
}

__global__ __launch_bounds__(256) void prep(
    const float* __restrict__ x,
    const float* __restrict__ w_attn,
    const float* __restrict__ w_proj,
    unsigned short* __restrict__ x_bf,
    unsigned short* __restrict__ wTa,
    unsigned short* __restrict__ wTp,
    float2* __restrict__ tab) {
    __shared__ unsigned short tile[64][68];
    int bid = blockIdx.x;
    int tid = threadIdx.x;
    if (bid < 4096) {
        int i = bid * 256 + tid;
        float4 v = ((const float4*)x)[i];
        ushort4 o;
        o.x = f2bf(v.x); o.y = f2bf(v.y); o.z = f2bf(v.z); o.w = f2bf(v.w);
        ((ushort4*)x_bf)[i] = o;
    } else if (bid < 4864) {
        int t = bid - 4096;
        transpose_body(w_attn, wTa, 1024, 3072, t % 48, t / 48, tid, tile);
    } else if (bid < 5120) {
        int t = bid - 4864;
        transpose_body(w_proj, wTp, 1024, 1024, t & 15, t >> 4, tid, tile);
    } else {
        int i = (bid - 5120) * 256 + tid;   // 65536 = 2048*32
        int t = i >> 5, d = i & 31;
        float inv_ts = exp2f(-0.41524101186092036f * (float)d);
        float ang = (float)t * inv_ts;
        tab[i] = make_float2(sinf(ang), cosf(ang));
    }
}

// ---------------- Fused QKV GEMM: BK=32, 32 KB LDS, all blocks resident ----
// 128x128 tile, BK=32 double-buffer = 32 KB -> 4-5 blocks/CU; 768 blocks all
// co-resident (zero dispatch tail). Counted vmcnt(4) pipeline.
// LDS layout [row][32] u16, phys col8 = k8 ^ ((row>>1)&3)  (2-way max = free).
// q scale folds log2(e): scale_q = 0.125 * 1.4426950408889634
__global__ __launch_bounds__(256) void gemm_qkv(
    const unsigned short* __restrict__ A,    // [4096][1024]
    const unsigned short* __restrict__ BT,   // [3072][1024]
    const float* __restrict__ bias,          // [3072]
    const float2* __restrict__ tab,          // [2048][32]
    unsigned short* __restrict__ qT,
    unsigned short* __restrict__ kT,
    unsigned short* __restrict__ vT) {
    __shared__ __align__(16) unsigned short smem[16384];  // 2 x (as|bs), 32 KB
    int tid = threadIdx.x;
    int lane = tid & 63;
    int w = tid >> 6;
    int wx = w & 1, wy = w >> 1;
    int l16 = lane & 15, quad = lane >> 4;
    // XCD-chunked swizzle: 768 blocks, 96/XCD, m-major chunks (A-panel reuse)
    int lin = blockIdx.x;
    int swz = (lin & 7) * 96 + (lin >> 3);
    int m0 = (swz / 24) * 128;
    int n0 = (swz % 24) * 128;
    int l2 = lane >> 2;                      // row-in-seg (0..15)
    int c4p = lane & 3;                      // physical col8 (0..3)

    floatx4 acc[4][4];
#pragma unroll
    for (int mi = 0; mi < 4; mi++)
#pragma unroll
        for (int ni = 0; ni < 4; ni++)
            acc[mi][ni] = (floatx4){0.f, 0.f, 0.f, 0.f};

    auto stage = [&](int bsel, int k0) {
        unsigned short* as = smem + bsel * 8192;
        unsigned short* bs = as + 4096;
#pragma unroll
        for (int i = 0; i < 2; i++) {
            int seg = w * 2 + i;             // 8 segs x 16 rows = 128 rows
            int row = seg * 16 + l2;
            int gk = (c4p ^ ((row >> 1) & 3)) * 8;   // inverse-swizzled source
            gld16(A + (size_t)(m0 + row) * 1024 + k0 + gk, &as[seg * 512]);
            gld16(BT + (size_t)(n0 + row) * 1024 + k0 + gk, &bs[seg * 512]);
        }
    };

    auto compute = [&](int bsel) {
        const unsigned short* as = smem + bsel * 8192;
        const unsigned short* bs = as + 4096;
        short8 af[4], bf[4];
#pragma unroll
        for (int mi = 0; mi < 4; mi++) {
            int r = wy * 64 + mi * 16 + l16;
            af[mi] = *(const short8*)&as[r * 32 + (quad ^ ((r >> 1) & 3)) * 8];
        }
#pragma unroll
        for (int ni = 0; ni < 4; ni++) {
            int r = wx * 64 + ni * 16 + l16;
            bf[ni] = *(const short8*)&bs[r * 32 + (quad ^ ((r >> 1) & 3)) * 8];
        }
#pragma unroll
        for (int mi = 0; mi < 4; mi++)
#pragma unroll
            for (int ni = 0; ni < 4; ni++)
                acc[mi][ni] = __builtin_amdgcn_mfma_f32_16x16x32_bf16(
                    af[mi], bf[ni], acc[mi][ni], 0, 0, 0);
    };

    stage(0, 0);                 // loads(0) in flight
    int cur = 0;
    for (int k0 = 0; k0 < 992; k0 += 32) {
        stage(cur ^ 1, k0 + 32);                       // loads(t+1): 4 vmem
        asm volatile("s_waitcnt vmcnt(4)" ::: "memory");  // loads(t) done
        __builtin_amdgcn_s_barrier();
        compute(cur);                                  // loads(t+1) still fly
        asm volatile("s_waitcnt lgkmcnt(0)" ::: "memory"); // my buf reads done
        __builtin_amdgcn_s_barrier();                  // all reads done
        cur ^= 1;
    }
    asm volatile("s_waitcnt vmcnt(0)" ::: "memory");
    __builtin_amdgcn_s_barrier();
    compute(cur);            // tail tile (k0 = 992)
    __syncthreads();         // all frag reads done before LDS reuse below

    int region = n0 >> 10;                    // 0=q, 1=k, 2=v
    int b = m0 >> 11;                         // tile never crosses batch
    float b0 = bias[n0 + wx * 64 + l16];
    float b1 = bias[n0 + wx * 64 + 16 + l16];
    float b2 = bias[n0 + wx * 64 + 32 + l16];
    float b3 = bias[n0 + wx * 64 + 48 + l16];

    if (region < 2) {
        // ---- q/k: RoPE pairs (d, d+32) = (acc ni, ni+2); bounce via LDS ----
        // 32 KB LDS only fits [64][136]: process the 128 rows in two halves.
        unsigned short* qk = region ? kT : qT;
        float scale = region ? 1.0f : 0.18033688011112042f;  // 0.125*log2(e)
        unsigned short* lq = smem;            // [64][136] u16 = 8704 <= 16384
        int c8 = tid & 7;
        int hl = (tid >> 3) & 1;
        int tl0 = tid >> 4;                   // 0..15
        int h = ((n0 & 1023) >> 6) + hl;
        unsigned short* ob = qk + (size_t)(b * 16 + h) * 2048 * 64;
#pragma unroll
        for (int hf = 0; hf < 2; hf++) {
            if (wy == hf) {                   // writer waves for this half
#pragma unroll
                for (int mi = 0; mi < 4; mi++)
#pragma unroll
                    for (int r = 0; r < 4; r++) {
                        int lr_ = mi * 16 + quad * 4 + r;         // 0..63
                        int t = (m0 & 2047) + hf * 64 + lr_;
                        float2 sc0 = tab[t * 32 + l16];
                        float2 sc1 = tab[t * 32 + 16 + l16];
                        float v1 = acc[mi][0][r] + b0, v2 = acc[mi][2][r] + b2;
                        float w1 = acc[mi][1][r] + b1, w2 = acc[mi][3][r] + b3;
                        unsigned short* orow = lq + lr_ * 136 + wx * 64;
                        orow[l16]      = f2bf((v1 * sc0.y - v2 * sc0.x) * scale);
                        orow[l16 + 32] = f2bf((v2 * sc0.y + v1 * sc0.x) * scale);
                        orow[l16 + 16] = f2bf((w1 * sc1.y - w2 * sc1.x) * scale);
                        orow[l16 + 48] = f2bf((w2 * sc1.y + w1 * sc1.x) * scale);
                    }
            }
            __syncthreads();
#pragma unroll
            for (int p = 0; p < 4; p++) {
                int rl = p * 16 + tl0;
                int t = (m0 & 2047) + hf * 64 + rl;
                short8 val = *(const short8*)&lq[rl * 136 + hl * 64 + c8 * 8];
                *(short8*)&ob[(size_t)t * 64 + c8 * 8] = val;
            }
            __syncthreads();                  // lq reads done before next half
        }
    } else {
        // ---- v: transpose 128x128 via LDS, write [bh][d][t] 16B runs ----
        // [128][128] u16 = 16384 fits the 32 KB smem exactly.
#pragma unroll
        for (int mi = 0; mi < 4; mi++)
#pragma unroll
            for (int ni = 0; ni < 4; ni++) {
                int d_loc = wx * 64 + ni * 16 + l16;
                int t_base = wy * 64 + mi * 16 + quad * 4;
                float bv = (ni == 0) ? b0 : (ni == 1) ? b1 : (ni == 2) ? b2 : b3;
                uint2 pk;
                pk.x = pk2bf(acc[mi][ni][0] + bv, acc[mi][ni][1] + bv);
                pk.y = pk2bf(acc[mi][ni][2] + bv, acc[mi][ni][3] + bv);
                int e = d_loc * 128 + (t_base ^ ((d_loc & 15) << 3));
                *(uint2*)&smem[e] = pk;
            }
        __syncthreads();
        int d_r = tid >> 1, half = tid & 1;
        int cv = (n0 - 2048) + d_r;
        int hh = cv >> 6, dd = cv & 63;
        int fofs = (d_r & 15) << 3;
        size_t vbase = ((size_t)(b * 16 + hh) * 64 + dd) * 2048 + (m0 & 2047);
#pragma unroll
        for (int c = 0; c < 8; c++) {
            int tc = half * 64 + c * 8;
            short8 val = *(const short8*)&smem[d_r * 128 + (tc ^ fofs)];
            *(short8*)&vT[vbase + tc] = val;
        }
    }
}

// ---------------- proj GEMM: counted-vmcnt 2-phase + XCD swizzle -----------
__global__ __launch_bounds__(256) void gemm_proj(
    const unsigned short* __restrict__ A,    // y_bf [4096][1024]
    const unsigned short* __restrict__ BT,   // wTp [1024][1024]
    const float* __restrict__ bias,
    float* __restrict__ out) {
    __shared__ __align__(16) unsigned short smem[24576];  // 2 x (as|bs), 48 KB
    int lane = threadIdx.x & 63;
    int w = threadIdx.x >> 6;
    int wx = w & 1, wy = w >> 1;             // wave tile 64(M) x 32(N)
    int l16 = lane & 15, quad = lane >> 4;
    // XCD-chunked swizzle: 512 blocks, 64/XCD = 4 m-panels x 16 n (3MB/L2)
    int lin = blockIdx.x;
    int swz = (lin & 7) * 64 + (lin >> 3);
    int m0 = (swz >> 4) * 128;
    int n0 = (swz & 15) * 64;
    int x = l16 & 7;
    int lr = lane >> 3;
    int gc = (lane & 7) ^ lr;

    floatx4 acc[4][2];
#pragma unroll
    for (int mi = 0; mi < 4; mi++)
#pragma unroll
        for (int ni = 0; ni < 2; ni++)
            acc[mi][ni] = (floatx4){0.f, 0.f, 0.f, 0.f};

    auto stage = [&](int bsel, int k0) {
        unsigned short* as = smem + bsel * 12288;
        unsigned short* bs = as + 8192;
#pragma unroll
        for (int i = 0; i < 6; i++) {
            int seg = w * 6 + i;              // 24 segments: 16 A + 8 B
            if (seg < 16) {
                int row = seg * 8 + lr;
                gld16(A + (size_t)(m0 + row) * 1024 + k0 + gc * 8, &as[seg * 512]);
            } else {
                int s2 = seg - 16;
                int row = s2 * 8 + lr;
                gld16(BT + (size_t)(n0 + row) * 1024 + k0 + gc * 8, &bs[s2 * 512]);
            }
        }
    };

    auto compute = [&](int bsel) {
        const unsigned short* as = smem + bsel * 12288;
        const unsigned short* bs = as + 8192;
#pragma unroll
        for (int kk = 0; kk < 2; kk++) {
            short8 af[4], bf[2];
#pragma unroll
            for (int mi = 0; mi < 4; mi++) {
                int r = wy * 64 + mi * 16 + l16;
                af[mi] = *(const short8*)&as[r * 64 + (((kk << 2) | quad) ^ x) * 8];
            }
#pragma unroll
            for (int ni = 0; ni < 2; ni++) {
                int r = wx * 32 + ni * 16 + l16;
                bf[ni] = *(const short8*)&bs[r * 64 + (((kk << 2) | quad) ^ x) * 8];
            }
#pragma unroll
            for (int mi = 0; mi < 4; mi++)
#pragma unroll
                for (int ni = 0; ni < 2; ni++)
                    acc[mi][ni] = __builtin_amdgcn_mfma_f32_16x16x32_bf16(
                        af[mi], bf[ni], acc[mi][ni], 0, 0, 0);
        }
    };

    stage(0, 0);
    int cur = 0;
    for (int k0 = 0; k0 < 960; k0 += 64) {
        stage(cur ^ 1, k0 + 64);                       // loads(t+1): 6 vmem
        asm volatile("s_waitcnt vmcnt(6)" ::: "memory");  // loads(t) done
        __builtin_amdgcn_s_barrier();
        compute(cur);
        asm volatile("s_waitcnt lgkmcnt(0)" ::: "memory");
        __builtin_amdgcn_s_barrier();
        cur ^= 1;
    }
    asm volatile("s_waitcnt vmcnt(0)" ::: "memory");
    __builtin_amdgcn_s_barrier();
    compute(cur);

#pragma unroll
    for (int mi = 0; mi < 4; mi++)
#pragma unroll
        for (int ni = 0; ni < 2; ni++) {
            int row = m0 + wy * 64 + mi * 16 + quad * 4;
            int col = n0 + wx * 32 + ni * 16 + l16;
            float bv = bias[col];
#pragma unroll
            for (int r = 0; r < 4; r++)
                out[(size_t)(row + r) * 1024 + col] = acc[mi][ni][r] + bv;
        }
}

// ---------------- Flash attention v5 + counted-vmcnt pipeline --------------
__global__ __launch_bounds__(256) void attn5(
    const unsigned short* __restrict__ qT,
    const unsigned short* __restrict__ kT,
    const unsigned short* __restrict__ vT,
    unsigned short* __restrict__ y) {
    __shared__ __align__(16) unsigned short kbuf[2][64 * 64];
    __shared__ __align__(16) unsigned short vbuf[2][64 * 64];
    __shared__ __align__(16) unsigned short pl[4][16 * 72];
    int lane = threadIdx.x & 63;
    int w = threadIdx.x >> 6;                  // 0..3
    int l16 = lane & 15, quad = lane >> 4;
    int blk = blockIdx.x;                      // 0..1023
    int t = 31 - (blk >> 5);                   // q-tile, longest (t=31) first
    int bh = blk & 31;
    int b = bh >> 4, h = bh & 15;
    int q0 = t * 64 + w * 16;
    const unsigned short* qp = qT + (size_t)bh * 2048 * 64;
    unsigned short* plw = pl[w];
    int x = l16 & 7;

    short8 qf0 = *(const short8*)(qp + (size_t)(q0 + l16) * 64 + quad * 8);
    short8 qf1 = *(const short8*)(qp + (size_t)(q0 + l16) * 64 + 32 + quad * 8);

    short8 ones;
#pragma unroll
    for (int j = 0; j < 8; j++) ones[j] = (short)0x3F80;   // bf16 1.0

    floatx4 acc[4];
#pragma unroll
    for (int ni = 0; ni < 4; ni++) acc[ni] = (floatx4){0.f, 0.f, 0.f, 0.f};
    floatx4 accl = (floatx4){0.f, 0.f, 0.f, 0.f};

    // staging: waves 0,1 load K (8 segs), waves 2,3 load V (8 segs).
    int lr8 = lane >> 3, l8 = lane & 7;
    const unsigned short* sp[4];
    unsigned short* ld0[4];
    int gstep;
    if (w < 2) {
        const unsigned short* kp = kT + (size_t)bh * 2048 * 64;
#pragma unroll
        for (int i = 0; i < 4; i++) {
            int seg = w * 4 + i;
            int row = seg * 8 + lr8;
            int c = l8 ^ (row & 7);
            sp[i] = kp + (size_t)row * 64 + c * 8;
            ld0[i] = &kbuf[0][seg * 512];
        }
        gstep = 4096;                          // 64 rows * 64 u16
    } else {
        const unsigned short* vp = vT + (size_t)bh * 64 * 2048;
#pragma unroll
        for (int i = 0; i < 4; i++) {
            int s = (w - 2) * 4 + i;
            int d = s * 8 + lr8;
            int c = l8 ^ (d & 7);
            sp[i] = vp + (size_t)d * 2048 + c * 8;
            ld0[i] = &vbuf[0][s * 512];
        }
        gstep = 64;                            // advance 64 t per KV block
    }

    auto stage = [&](int bi) {
#pragma unroll
        for (int i = 0; i < 4; i++) {
            gld16(sp[i], ld0[i] + bi * 4096);
            sp[i] += gstep;
        }
    };

    int L = t + 1;
    int query = q0 + l16;
    stage(0);
    int cur = 0;
    for (int it = 0; it < L; it++) {
        if (it + 1 < L) {                      // block-uniform branch
            stage(cur ^ 1);                    // loads(t+1): 4 vmem in flight
            asm volatile("s_waitcnt vmcnt(4)" ::: "memory");  // loads(t) done
        } else {
            asm volatile("s_waitcnt vmcnt(0)" ::: "memory");
        }
        __builtin_amdgcn_s_barrier();
        const unsigned short* kb = kbuf[cur];
        const unsigned short* vb = vbuf[cur];
        bool diag = (it == t);                 // block-uniform
        floatx4 s4[4];
        __builtin_amdgcn_s_setprio(1);
#pragma unroll
        for (int c = 0; c < 4; c++) {
            int r = c * 16 + l16;
            short8 kf0 = *(const short8*)&kb[r * 64 + ((quad) ^ x) * 8];
            short8 kf1 = *(const short8*)&kb[r * 64 + ((quad | 4) ^ x) * 8];
            floatx4 z = (floatx4){0.f, 0.f, 0.f, 0.f};
            z = __builtin_amdgcn_mfma_f32_16x16x32_bf16(kf0, qf0, z, 0, 0, 0);
            z = __builtin_amdgcn_mfma_f32_16x16x32_bf16(kf1, qf1, z, 0, 0, 0);
            s4[c] = z;
        }
        __builtin_amdgcn_s_setprio(0);
        int j0 = it * 64;
#pragma unroll
        for (int c = 0; c < 4; c++) {
            float p[4];
#pragma unroll
            for (int r = 0; r < 4; r++) {
                float e = __builtin_amdgcn_exp2f(s4[c][r]);
                if (diag) {
                    int key = j0 + c * 16 + quad * 4 + r;
                    e = (key <= query) ? e : 0.f;
                }
                p[r] = e;
            }
            uint2 pk;
            pk.x = cvtpk(p[0], p[1]);
            pk.y = cvtpk(p[2], p[3]);
            *(uint2*)&plw[l16 * 72 + c * 16 + quad * 4] = pk;
        }
        short8 pa0 = *(const short8*)&plw[l16 * 72 + quad * 8];
        short8 pa1 = *(const short8*)&plw[l16 * 72 + 32 + quad * 8];
        __builtin_amdgcn_s_setprio(1);
        accl = __builtin_amdgcn_mfma_f32_16x16x32_bf16(pa0, ones, accl, 0, 0, 0);
        accl = __builtin_amdgcn_mfma_f32_16x16x32_bf16(pa1, ones, accl, 0, 0, 0);
#pragma unroll
        for (int ni = 0; ni < 4; ni++) {
            int d = ni * 16 + l16;
            short8 vf0 = *(const short8*)&vb[d * 64 + ((quad) ^ x) * 8];
            short8 vf1 = *(const short8*)&vb[d * 64 + ((quad | 4) ^ x) * 8];
            acc[ni] = __builtin_amdgcn_mfma_f32_16x16x32_bf16(pa0, vf0, acc[ni], 0, 0, 0);
            acc[ni] = __builtin_amdgcn_mfma_f32_16x16x32_bf16(pa1, vf1, acc[ni], 0, 0, 0);
        }
        __builtin_amdgcn_s_setprio(0);
        asm volatile("s_waitcnt lgkmcnt(0)" ::: "memory");  // buf reads done
        __builtin_amdgcn_s_barrier();          // safe to refill buf[cur]
        cur ^= 1;
    }

    float inv[4];
#pragma unroll
    for (int r = 0; r < 4; r++) inv[r] = 1.f / accl[r];
#pragma unroll
    for (int ni = 0; ni < 4; ni++)
#pragma unroll
        for (int r = 0; r < 4; r++) {
            int tr = q0 + quad * 4 + r;
            y[((size_t)(b * 2048 + tr)) * 1024 + h * 64 + ni * 16 + l16] =
                f2bf(acc[ni][r] * inv[r]);
        }
}

extern "C" void kernel_launch(void* const* d_in, const int* in_sizes, int n_in,
                              void* d_out, int out_size, void* d_ws, size_t ws_size,
                              hipStream_t stream) {
    const float* x      = (const float*)d_in[0];
    const float* w_attn = (const float*)d_in[1];
    const float* b_attn = (const float*)d_in[2];
    const float* w_proj = (const float*)d_in[3];
    const float* b_proj = (const float*)d_in[4];
    float* out = (float*)d_out;

    char* ws = (char*)d_ws;
    unsigned short* x_bf = (unsigned short*)ws;                    //  8 MB
    unsigned short* wTa  = (unsigned short*)(ws + (8ull << 20));   //  6 MB
    unsigned short* wTp  = (unsigned short*)(ws + (14ull << 20));  //  2 MB
    unsigned short* qTb  = (unsigned short*)(ws + (16ull << 20));  //  8 MB
    unsigned short* kTb  = (unsigned short*)(ws + (24ull << 20));  //  8 MB
    unsigned short* vTb  = (unsigned short*)(ws + (32ull << 20));  //  8 MB
    float2*         tab  = (float2*)(ws + (40ull << 20));          // 512 KB
    unsigned short* y_bf = x_bf;  // alias: x_bf dead after QKV GEMM

    prep<<<5376, 256, 0, stream>>>(x, w_attn, w_proj, x_bf, wTa, wTp, tab);
    gemm_qkv<<<768, 256, 0, stream>>>(x_bf, wTa, b_attn, tab, qTb, kTb, vTb);
    attn5<<<1024, 256, 0, stream>>>(qTb, kTb, vTb, y_bf);
    gemm_proj<<<512, 256, 0, stream>>>(y_bf, wTp, b_proj, out);
}

// Round 7
// 168.006 us; speedup vs baseline: 1.0559x; 1.0559x over previous
//
#include <hip/hip_runtime.h>
#include <hip/hip_bf16.h>

// Problem constants
// B=2, T=2048, C=1024, H=16, HD=64, 3C=3072, M=B*T=4096

typedef __attribute__((ext_vector_type(8))) short short8;
typedef __attribute__((ext_vector_type(4))) float floatx4;

__device__ __forceinline__ unsigned short f2bf(float f) {
    union { float f; unsigned int u; } v; v.f = f;
    unsigned int r = v.u + 0x7FFFu + ((v.u >> 16) & 1u);
    return (unsigned short)(r >> 16);
}

// pack 2 fp32 -> 2 bf16 (round-half-up) in one v_perm_b32; result mem order: a,b
__device__ __forceinline__ unsigned int pk2bf(float a, float b) {
    union { float f; unsigned int u; } ua, ub;
    ua.f = a; ub.f = b;
    return __builtin_amdgcn_perm(ub.u + 0x8000u, ua.u + 0x8000u, 0x07060302u);
}

// 2 fp32 -> packed bf16x2 (RNE) in one instruction; mem order: a (low), b (high)
__device__ __forceinline__ unsigned int cvtpk(float a, float b) {
    unsigned int r;
    asm("v_cvt_pk_bf16_f32 %0, %1, %2" : "=v"(r) : "v"(a), "v"(b));
    return r;
}

__device__ __forceinline__ void gld16(const void* g, void* l) {
    __builtin_amdgcn_global_load_lds(
        (const __attribute__((address_space(1))) unsigned int*)g,
        (__attribute__((address_space(3))) unsigned int*)l, 16, 0, 0);
}

// ---------------- fused prep: cast x, transpose w_attn/w_proj, rope table --
__device__ __forceinline__ void transpose_body(
    const float* __restrict__ in, unsigned short* __restrict__ out,
    int R, int NC, int bx, int by, int tid,
    unsigned short (*tile)[68]) {
    int r0 = by * 64, c0 = bx * 64;
    // vectorized load phase: float4 per thread, 4 passes of 16 rows
    int c4 = (tid & 15) * 4, rr = tid >> 4;
#pragma unroll
    for (int i = 0; i < 4; i++) {
        int row = rr + i * 16;
        float4 v = *(const float4*)&in[(size_t)(r0 + row) * NC + c0 + c4];
        ushort4 o;
        o.x = f2bf(v.x); o.y = f2bf(v.y); o.z = f2bf(v.z); o.w = f2bf(v.w);
        *(ushort4*)&tile[row][c4] = o;
    }
    __syncthreads();
    int col = tid & 63, rr2 = tid >> 6;
#pragma unroll
    for (int i = 0; i < 16; i++) {
        int orow = rr2 + i * 4;
        out[(size_t)(c0 + orow) * R + r0 + col] = tile[col][orow];
    }
}

__global__ __launch_bounds__(256) void prep(
    const float* __restrict__ x,
    const float* __restrict__ w_attn,
    const float* __restrict__ w_proj,
    unsigned short* __restrict__ x_bf,
    unsigned short* __restrict__ wTa,
    unsigned short* __restrict__ wTp,
    float2* __restrict__ tab) {
    __shared__ unsigned short tile[64][68];
    int bid = blockIdx.x;
    int tid = threadIdx.x;
    if (bid < 4096) {
        int i = bid * 256 + tid;
        float4 v = ((const float4*)x)[i];
        ushort4 o;
        o.x = f2bf(v.x); o.y = f2bf(v.y); o.z = f2bf(v.z); o.w = f2bf(v.w);
        ((ushort4*)x_bf)[i] = o;
    } else if (bid < 4864) {
        int t = bid - 4096;
        transpose_body(w_attn, wTa, 1024, 3072, t % 48, t / 48, tid, tile);
    } else if (bid < 5120) {
        int t = bid - 4864;
        transpose_body(w_proj, wTp, 1024, 1024, t & 15, t >> 4, tid, tile);
    } else {
        int i = (bid - 5120) * 256 + tid;   // 65536 = 2048*32
        int t = i >> 5, d = i & 31;
        float inv_ts = exp2f(-0.41524101186092036f * (float)d);
        float ang = (float)t * inv_ts;
        tab[i] = make_float2(sinf(ang), cosf(ang));
    }
}

// ---------------- Fused QKV GEMM: counted-vmcnt 2-phase, BK=64 -------------
// XCD swizzle 8m x 12n per chunk: per-XCD L2 working set A 2MB + B 3MB = 5MB
// (was 4m x 24n = 7MB -> B thrash, FETCH 43MB).
// q scale folds log2(e): scale_q = 0.125 * 1.4426950408889634
__global__ __launch_bounds__(256) void gemm_qkv(
    const unsigned short* __restrict__ A,    // [4096][1024]
    const unsigned short* __restrict__ BT,   // [3072][1024]
    const float* __restrict__ bias,          // [3072]
    const float2* __restrict__ tab,          // [2048][32]
    unsigned short* __restrict__ qT,
    unsigned short* __restrict__ kT,
    unsigned short* __restrict__ vT) {
    __shared__ __align__(16) unsigned short smem[32768];  // 2 x (as|bs), 64 KB
    int tid = threadIdx.x;
    int lane = tid & 63;
    int w = tid >> 6;
    int wx = w & 1, wy = w >> 1;
    int l16 = lane & 15, quad = lane >> 4;
    // XCD-chunked swizzle: 768 blocks, 96/XCD as 8 m-panels x 12 n-tiles
    int lin = blockIdx.x;
    int xcd = lin & 7, idx = lin >> 3;        // idx 0..95
    int mb = (xcd >> 1) * 8 + idx / 12;       // 0..31
    int nb = (xcd & 1) * 12 + idx % 12;       // 0..23
    int m0 = mb * 128;
    int n0 = nb * 128;
    int x = l16 & 7;
    int lr = lane >> 3;
    int gc = (lane & 7) ^ lr;

    floatx4 acc[4][4];
#pragma unroll
    for (int mi = 0; mi < 4; mi++)
#pragma unroll
        for (int ni = 0; ni < 4; ni++)
            acc[mi][ni] = (floatx4){0.f, 0.f, 0.f, 0.f};

    auto stage = [&](int bsel, int k0) {
        unsigned short* as = smem + bsel * 16384;
        unsigned short* bs = as + 8192;
#pragma unroll
        for (int i = 0; i < 4; i++) {
            int seg = w * 4 + i;
            int row = seg * 8 + lr;
            gld16(A + (size_t)(m0 + row) * 1024 + k0 + gc * 8, &as[seg * 512]);
            gld16(BT + (size_t)(n0 + row) * 1024 + k0 + gc * 8, &bs[seg * 512]);
        }
    };

    auto compute = [&](int bsel) {
        const unsigned short* as = smem + bsel * 16384;
        const unsigned short* bs = as + 8192;
#pragma unroll
        for (int kk = 0; kk < 2; kk++) {
            short8 af[4], bf[4];
#pragma unroll
            for (int mi = 0; mi < 4; mi++) {
                int r = wy * 64 + mi * 16 + l16;
                af[mi] = *(const short8*)&as[r * 64 + (((kk << 2) | quad) ^ x) * 8];
            }
#pragma unroll
            for (int ni = 0; ni < 4; ni++) {
                int r = wx * 64 + ni * 16 + l16;
                bf[ni] = *(const short8*)&bs[r * 64 + (((kk << 2) | quad) ^ x) * 8];
            }
#pragma unroll
            for (int mi = 0; mi < 4; mi++)
#pragma unroll
                for (int ni = 0; ni < 4; ni++)
                    acc[mi][ni] = __builtin_amdgcn_mfma_f32_16x16x32_bf16(
                        af[mi], bf[ni], acc[mi][ni], 0, 0, 0);
        }
    };

    stage(0, 0);                 // loads(0) in flight
    int cur = 0;
    for (int k0 = 0; k0 < 960; k0 += 64) {
        stage(cur ^ 1, k0 + 64);                       // loads(t+1): 8 vmem
        asm volatile("s_waitcnt vmcnt(8)" ::: "memory");  // loads(t) done
        __builtin_amdgcn_s_barrier();
        compute(cur);                                  // loads(t+1) still fly
        asm volatile("s_waitcnt lgkmcnt(0)" ::: "memory"); // my buf reads done
        __builtin_amdgcn_s_barrier();                  // all reads done
        cur ^= 1;
    }
    asm volatile("s_waitcnt vmcnt(0)" ::: "memory");
    __builtin_amdgcn_s_barrier();
    compute(cur);            // tail tile (k0 = 960)
    __syncthreads();         // all frag reads done before LDS reuse below

    int region = n0 >> 10;                    // 0=q, 1=k, 2=v
    int b = m0 >> 11;                         // tile never crosses batch
    float b0 = bias[n0 + wx * 64 + l16];
    float b1 = bias[n0 + wx * 64 + 16 + l16];
    float b2 = bias[n0 + wx * 64 + 32 + l16];
    float b3 = bias[n0 + wx * 64 + 48 + l16];

    if (region < 2) {
        // ---- q/k: RoPE pairs (d, d+32) = (acc ni, ni+2); bounce via LDS ----
        unsigned short* qk = region ? kT : qT;
        float scale = region ? 1.0f : 0.18033688011112042f;  // 0.125*log2(e)
        unsigned short* lq = smem;
#pragma unroll
        for (int mi = 0; mi < 4; mi++)
#pragma unroll
            for (int r = 0; r < 4; r++) {
                int tl = wy * 64 + mi * 16 + quad * 4 + r;
                int t = (m0 & 2047) + tl;
                float2 sc0 = tab[t * 32 + l16];
                float2 sc1 = tab[t * 32 + 16 + l16];
                float v1 = acc[mi][0][r] + b0, v2 = acc[mi][2][r] + b2;
                float w1 = acc[mi][1][r] + b1, w2 = acc[mi][3][r] + b3;
                unsigned short* orow = lq + tl * 136 + wx * 64;
                orow[l16]      = f2bf((v1 * sc0.y - v2 * sc0.x) * scale);
                orow[l16 + 32] = f2bf((v2 * sc0.y + v1 * sc0.x) * scale);
                orow[l16 + 16] = f2bf((w1 * sc1.y - w2 * sc1.x) * scale);
                orow[l16 + 48] = f2bf((w2 * sc1.y + w1 * sc1.x) * scale);
            }
        __syncthreads();
        int c8 = tid & 7;
        int hl = (tid >> 3) & 1;
        int tl0 = tid >> 4;                   // 0..15
        int h = ((n0 & 1023) >> 6) + hl;
        unsigned short* ob = qk + (size_t)(b * 16 + h) * 2048 * 64;
#pragma unroll
        for (int p = 0; p < 8; p++) {
            int tl = p * 16 + tl0;
            int t = (m0 & 2047) + tl;
            short8 val = *(const short8*)&lq[tl * 136 + hl * 64 + c8 * 8];
            *(short8*)&ob[(size_t)t * 64 + c8 * 8] = val;
        }
    } else {
        // ---- v: transpose 128x128 via LDS, write [bh][d][t] 16B runs ----
#pragma unroll
        for (int mi = 0; mi < 4; mi++)
#pragma unroll
            for (int ni = 0; ni < 4; ni++) {
                int d_loc = wx * 64 + ni * 16 + l16;
                int t_base = wy * 64 + mi * 16 + quad * 4;
                float bv = (ni == 0) ? b0 : (ni == 1) ? b1 : (ni == 2) ? b2 : b3;
                uint2 pk;
                pk.x = pk2bf(acc[mi][ni][0] + bv, acc[mi][ni][1] + bv);
                pk.y = pk2bf(acc[mi][ni][2] + bv, acc[mi][ni][3] + bv);
                int e = d_loc * 128 + (t_base ^ ((d_loc & 15) << 3));
                *(uint2*)&smem[e] = pk;
            }
        __syncthreads();
        int d_r = tid >> 1, half = tid & 1;
        int cv = (n0 - 2048) + d_r;
        int hh = cv >> 6, dd = cv & 63;
        int fofs = (d_r & 15) << 3;
        size_t vbase = ((size_t)(b * 16 + hh) * 64 + dd) * 2048 + (m0 & 2047);
#pragma unroll
        for (int c = 0; c < 8; c++) {
            int tc = half * 64 + c * 8;
            short8 val = *(const short8*)&smem[d_r * 128 + (tc ^ fofs)];
            *(short8*)&vT[vbase + tc] = val;
        }
    }
}

// ---------------- proj GEMM: counted-vmcnt 2-phase + XCD swizzle -----------
__global__ __launch_bounds__(256) void gemm_proj(
    const unsigned short* __restrict__ A,    // y_bf [4096][1024]
    const unsigned short* __restrict__ BT,   // wTp [1024][1024]
    const float* __restrict__ bias,
    float* __restrict__ out) {
    __shared__ __align__(16) unsigned short smem[24576];  // 2 x (as|bs), 48 KB
    int lane = threadIdx.x & 63;
    int w = threadIdx.x >> 6;
    int wx = w & 1, wy = w >> 1;             // wave tile 64(M) x 32(N)
    int l16 = lane & 15, quad = lane >> 4;
    // XCD-chunked swizzle: 512 blocks, 64/XCD = 4 m-panels x 16 n (3MB/L2)
    int lin = blockIdx.x;
    int swz = (lin & 7) * 64 + (lin >> 3);
    int m0 = (swz >> 4) * 128;
    int n0 = (swz & 15) * 64;
    int x = l16 & 7;
    int lr = lane >> 3;
    int gc = (lane & 7) ^ lr;

    floatx4 acc[4][2];
#pragma unroll
    for (int mi = 0; mi < 4; mi++)
#pragma unroll
        for (int ni = 0; ni < 2; ni++)
            acc[mi][ni] = (floatx4){0.f, 0.f, 0.f, 0.f};

    auto stage = [&](int bsel, int k0) {
        unsigned short* as = smem + bsel * 12288;
        unsigned short* bs = as + 8192;
#pragma unroll
        for (int i = 0; i < 6; i++) {
            int seg = w * 6 + i;              // 24 segments: 16 A + 8 B
            if (seg < 16) {
                int row = seg * 8 + lr;
                gld16(A + (size_t)(m0 + row) * 1024 + k0 + gc * 8, &as[seg * 512]);
            } else {
                int s2 = seg - 16;
                int row = s2 * 8 + lr;
                gld16(BT + (size_t)(n0 + row) * 1024 + k0 + gc * 8, &bs[s2 * 512]);
            }
        }
    };

    auto compute = [&](int bsel) {
        const unsigned short* as = smem + bsel * 12288;
        const unsigned short* bs = as + 8192;
#pragma unroll
        for (int kk = 0; kk < 2; kk++) {
            short8 af[4], bf[2];
#pragma unroll
            for (int mi = 0; mi < 4; mi++) {
                int r = wy * 64 + mi * 16 + l16;
                af[mi] = *(const short8*)&as[r * 64 + (((kk << 2) | quad) ^ x) * 8];
            }
#pragma unroll
            for (int ni = 0; ni < 2; ni++) {
                int r = wx * 32 + ni * 16 + l16;
                bf[ni] = *(const short8*)&bs[r * 64 + (((kk << 2) | quad) ^ x) * 8];
            }
#pragma unroll
            for (int mi = 0; mi < 4; mi++)
#pragma unroll
                for (int ni = 0; ni < 2; ni++)
                    acc[mi][ni] = __builtin_amdgcn_mfma_f32_16x16x32_bf16(
                        af[mi], bf[ni], acc[mi][ni], 0, 0, 0);
        }
    };

    stage(0, 0);
    int cur = 0;
    for (int k0 = 0; k0 < 960; k0 += 64) {
        stage(cur ^ 1, k0 + 64);                       // loads(t+1): 6 vmem
        asm volatile("s_waitcnt vmcnt(6)" ::: "memory");  // loads(t) done
        __builtin_amdgcn_s_barrier();
        compute(cur);
        asm volatile("s_waitcnt lgkmcnt(0)" ::: "memory");
        __builtin_amdgcn_s_barrier();
        cur ^= 1;
    }
    asm volatile("s_waitcnt vmcnt(0)" ::: "memory");
    __builtin_amdgcn_s_barrier();
    compute(cur);

#pragma unroll
    for (int mi = 0; mi < 4; mi++)
#pragma unroll
        for (int ni = 0; ni < 2; ni++) {
            int row = m0 + wy * 64 + mi * 16 + quad * 4;
            int col = n0 + wx * 32 + ni * 16 + l16;
            float bv = bias[col];
#pragma unroll
            for (int r = 0; r < 4; r++)
                out[(size_t)(row + r) * 1024 + col] = acc[mi][ni][r] + bv;
        }
}

// ---------------- Flash attention v5 + counted-vmcnt + bh-per-XCD grouping -
// blockIdx remap: xcd = blk&7 owns bh in [xcd*4, xcd*4+4) -> per-XCD K/V
// working set 4 x 512KB = 2MB (L2-resident; was 16MB streamed via L3).
// Longest-tile-first preserved: first 32 blocks are all bh at t=31.
__global__ __launch_bounds__(256) void attn5(
    const unsigned short* __restrict__ qT,
    const unsigned short* __restrict__ kT,
    const unsigned short* __restrict__ vT,
    unsigned short* __restrict__ y) {
    __shared__ __align__(16) unsigned short kbuf[2][64 * 64];
    __shared__ __align__(16) unsigned short vbuf[2][64 * 64];
    __shared__ __align__(16) unsigned short pl[4][16 * 72];
    int lane = threadIdx.x & 63;
    int w = threadIdx.x >> 6;                  // 0..3
    int l16 = lane & 15, quad = lane >> 4;
    int blk = blockIdx.x;                      // 0..1023
    int xcd = blk & 7, rix = blk >> 3;         // rix 0..127
    int bh = xcd * 4 + (rix & 3);              // 4 bh per XCD
    int t = 31 - (rix >> 2);                   // q-tile, longest (t=31) first
    int b = bh >> 4, h = bh & 15;
    int q0 = t * 64 + w * 16;
    const unsigned short* qp = qT + (size_t)bh * 2048 * 64;
    unsigned short* plw = pl[w];
    int x = l16 & 7;

    short8 qf0 = *(const short8*)(qp + (size_t)(q0 + l16) * 64 + quad * 8);
    short8 qf1 = *(const short8*)(qp + (size_t)(q0 + l16) * 64 + 32 + quad * 8);

    short8 ones;
#pragma unroll
    for (int j = 0; j < 8; j++) ones[j] = (short)0x3F80;   // bf16 1.0

    floatx4 acc[4];
#pragma unroll
    for (int ni = 0; ni < 4; ni++) acc[ni] = (floatx4){0.f, 0.f, 0.f, 0.f};
    floatx4 accl = (floatx4){0.f, 0.f, 0.f, 0.f};

    // staging: waves 0,1 load K (8 segs), waves 2,3 load V (8 segs).
    int lr8 = lane >> 3, l8 = lane & 7;
    const unsigned short* sp[4];
    unsigned short* ld0[4];
    int gstep;
    if (w < 2) {
        const unsigned short* kp = kT + (size_t)bh * 2048 * 64;
#pragma unroll
        for (int i = 0; i < 4; i++) {
            int seg = w * 4 + i;
            int row = seg * 8 + lr8;
            int c = l8 ^ (row & 7);
            sp[i] = kp + (size_t)row * 64 + c * 8;
            ld0[i] = &kbuf[0][seg * 512];
        }
        gstep = 4096;                          // 64 rows * 64 u16
    } else {
        const unsigned short* vp = vT + (size_t)bh * 64 * 2048;
#pragma unroll
        for (int i = 0; i < 4; i++) {
            int s = (w - 2) * 4 + i;
            int d = s * 8 + lr8;
            int c = l8 ^ (d & 7);
            sp[i] = vp + (size_t)d * 2048 + c * 8;
            ld0[i] = &vbuf[0][s * 512];
        }
        gstep = 64;                            // advance 64 t per KV block
    }

    auto stage = [&](int bi) {
#pragma unroll
        for (int i = 0; i < 4; i++) {
            gld16(sp[i], ld0[i] + bi * 4096);
            sp[i] += gstep;
        }
    };

    int L = t + 1;
    int query = q0 + l16;
    stage(0);
    int cur = 0;
    for (int it = 0; it < L; it++) {
        if (it + 1 < L) {                      // block-uniform branch
            stage(cur ^ 1);                    // loads(t+1): 4 vmem in flight
            asm volatile("s_waitcnt vmcnt(4)" ::: "memory");  // loads(t) done
        } else {
            asm volatile("s_waitcnt vmcnt(0)" ::: "memory");
        }
        __builtin_amdgcn_s_barrier();
        const unsigned short* kb = kbuf[cur];
        const unsigned short* vb = vbuf[cur];
        bool diag = (it == t);                 // block-uniform
        floatx4 s4[4];
        __builtin_amdgcn_s_setprio(1);
#pragma unroll
        for (int c = 0; c < 4; c++) {
            int r = c * 16 + l16;
            short8 kf0 = *(const short8*)&kb[r * 64 + ((quad) ^ x) * 8];
            short8 kf1 = *(const short8*)&kb[r * 64 + ((quad | 4) ^ x) * 8];
            floatx4 z = (floatx4){0.f, 0.f, 0.f, 0.f};
            z = __builtin_amdgcn_mfma_f32_16x16x32_bf16(kf0, qf0, z, 0, 0, 0);
            z = __builtin_amdgcn_mfma_f32_16x16x32_bf16(kf1, qf1, z, 0, 0, 0);
            s4[c] = z;
        }
        __builtin_amdgcn_s_setprio(0);
        int j0 = it * 64;
#pragma unroll
        for (int c = 0; c < 4; c++) {
            float p[4];
#pragma unroll
            for (int r = 0; r < 4; r++) {
                float e = __builtin_amdgcn_exp2f(s4[c][r]);
                if (diag) {
                    int key = j0 + c * 16 + quad * 4 + r;
                    e = (key <= query) ? e : 0.f;
                }
                p[r] = e;
            }
            uint2 pk;
            pk.x = cvtpk(p[0], p[1]);
            pk.y = cvtpk(p[2], p[3]);
            *(uint2*)&plw[l16 * 72 + c * 16 + quad * 4] = pk;
        }
        short8 pa0 = *(const short8*)&plw[l16 * 72 + quad * 8];
        short8 pa1 = *(const short8*)&plw[l16 * 72 + 32 + quad * 8];
        __builtin_amdgcn_s_setprio(1);
        accl = __builtin_amdgcn_mfma_f32_16x16x32_bf16(pa0, ones, accl, 0, 0, 0);
        accl = __builtin_amdgcn_mfma_f32_16x16x32_bf16(pa1, ones, accl, 0, 0, 0);
#pragma unroll
        for (int ni = 0; ni < 4; ni++) {
            int d = ni * 16 + l16;
            short8 vf0 = *(const short8*)&vb[d * 64 + ((quad) ^ x) * 8];
            short8 vf1 = *(const short8*)&vb[d * 64 + ((quad | 4) ^ x) * 8];
            acc[ni] = __builtin_amdgcn_mfma_f32_16x16x32_bf16(pa0, vf0, acc[ni], 0, 0, 0);
            acc[ni] = __builtin_amdgcn_mfma_f32_16x16x32_bf16(pa1, vf1, acc[ni], 0, 0, 0);
        }
        __builtin_amdgcn_s_setprio(0);
        asm volatile("s_waitcnt lgkmcnt(0)" ::: "memory");  // buf reads done
        __builtin_amdgcn_s_barrier();          // safe to refill buf[cur]
        cur ^= 1;
    }

    float inv[4];
#pragma unroll
    for (int r = 0; r < 4; r++) inv[r] = 1.f / accl[r];
#pragma unroll
    for (int ni = 0; ni < 4; ni++)
#pragma unroll
        for (int r = 0; r < 4; r++) {
            int tr = q0 + quad * 4 + r;
            y[((size_t)(b * 2048 + tr)) * 1024 + h * 64 + ni * 16 + l16] =
                f2bf(acc[ni][r] * inv[r]);
        }
}

extern "C" void kernel_launch(void* const* d_in, const int* in_sizes, int n_in,
                              void* d_out, int out_size, void* d_ws, size_t ws_size,
                              hipStream_t stream) {
    const float* x      = (const float*)d_in[0];
    const float* w_attn = (const float*)d_in[1];
    const float* b_attn = (const float*)d_in[2];
    const float* w_proj = (const float*)d_in[3];
    const float* b_proj = (const float*)d_in[4];
    float* out = (float*)d_out;

    char* ws = (char*)d_ws;
    unsigned short* x_bf = (unsigned short*)ws;                    //  8 MB
    unsigned short* wTa  = (unsigned short*)(ws + (8ull << 20));   //  6 MB
    unsigned short* wTp  = (unsigned short*)(ws + (14ull << 20));  //  2 MB
    unsigned short* qTb  = (unsigned short*)(ws + (16ull << 20));  //  8 MB
    unsigned short* kTb  = (unsigned short*)(ws + (24ull << 20));  //  8 MB
    unsigned short* vTb  = (unsigned short*)(ws + (32ull << 20));  //  8 MB
    float2*         tab  = (float2*)(ws + (40ull << 20));          // 512 KB
    unsigned short* y_bf = x_bf;  // alias: x_bf dead after QKV GEMM

    prep<<<5376, 256, 0, stream>>>(x, w_attn, w_proj, x_bf, wTa, wTp, tab);
    gemm_qkv<<<768, 256, 0, stream>>>(x_bf, wTa, b_attn, tab, qTb, kTb, vTb);
    attn5<<<1024, 256, 0, stream>>>(qTb, kTb, vTb, y_bf);
    gemm_proj<<<512, 256, 0, stream>>>(y_bf, wTp, b_proj, out);
}

// Round 8
// 162.059 us; speedup vs baseline: 1.0947x; 1.0367x over previous
//
#include <hip/hip_runtime.h>
#include <hip/hip_bf16.h>

// Problem constants
// B=2, T=2048, C=1024, H=16, HD=64, 3C=3072, M=B*T=4096

typedef __attribute__((ext_vector_type(8))) short short8;
typedef __attribute__((ext_vector_type(4))) float floatx4;

__device__ __forceinline__ unsigned short f2bf(float f) {
    union { float f; unsigned int u; } v; v.f = f;
    unsigned int r = v.u + 0x7FFFu + ((v.u >> 16) & 1u);
    return (unsigned short)(r >> 16);
}

// pack 2 fp32 -> 2 bf16 (round-half-up) in one v_perm_b32; result mem order: a,b
__device__ __forceinline__ unsigned int pk2bf(float a, float b) {
    union { float f; unsigned int u; } ua, ub;
    ua.f = a; ub.f = b;
    return __builtin_amdgcn_perm(ub.u + 0x8000u, ua.u + 0x8000u, 0x07060302u);
}

// 2 fp32 -> packed bf16x2 (RNE) in one instruction; mem order: a (low), b (high)
__device__ __forceinline__ unsigned int cvtpk(float a, float b) {
    unsigned int r;
    asm("v_cvt_pk_bf16_f32 %0, %1, %2" : "=v"(r) : "v"(a), "v"(b));
    return r;
}

__device__ __forceinline__ void gld16(const void* g, void* l) {
    __builtin_amdgcn_global_load_lds(
        (const __attribute__((address_space(1))) unsigned int*)g,
        (__attribute__((address_space(3))) unsigned int*)l, 16, 0, 0);
}

// ---------------- fused prep: cast x, transpose w_attn/w_proj, rope table --
__device__ __forceinline__ void transpose_body(
    const float* __restrict__ in, unsigned short* __restrict__ out,
    int R, int NC, int bx, int by, int tid,
    unsigned short (*tile)[68]) {
    int r0 = by * 64, c0 = bx * 64;
    // vectorized load phase: float4 per thread, 4 passes of 16 rows
    int c4 = (tid & 15) * 4, rr = tid >> 4;
#pragma unroll
    for (int i = 0; i < 4; i++) {
        int row = rr + i * 16;
        float4 v = *(const float4*)&in[(size_t)(r0 + row) * NC + c0 + c4];
        ushort4 o;
        o.x = f2bf(v.x); o.y = f2bf(v.y); o.z = f2bf(v.z); o.w = f2bf(v.w);
        *(ushort4*)&tile[row][c4] = o;
    }
    __syncthreads();
    int col = tid & 63, rr2 = tid >> 6;
#pragma unroll
    for (int i = 0; i < 16; i++) {
        int orow = rr2 + i * 4;
        out[(size_t)(c0 + orow) * R + r0 + col] = tile[col][orow];
    }
}

__global__ __launch_bounds__(256) void prep(
    const float* __restrict__ x,
    const float* __restrict__ w_attn,
    const float* __restrict__ w_proj,
    unsigned short* __restrict__ x_bf,
    unsigned short* __restrict__ wTa,
    unsigned short* __restrict__ wTp,
    float2* __restrict__ tab) {
    __shared__ unsigned short tile[64][68];
    int bid = blockIdx.x;
    int tid = threadIdx.x;
    if (bid < 4096) {
        int i = bid * 256 + tid;
        float4 v = ((const float4*)x)[i];
        ushort4 o;
        o.x = f2bf(v.x); o.y = f2bf(v.y); o.z = f2bf(v.z); o.w = f2bf(v.w);
        ((ushort4*)x_bf)[i] = o;
    } else if (bid < 4864) {
        int t = bid - 4096;
        transpose_body(w_attn, wTa, 1024, 3072, t % 48, t / 48, tid, tile);
    } else if (bid < 5120) {
        int t = bid - 4864;
        transpose_body(w_proj, wTp, 1024, 1024, t & 15, t >> 4, tid, tile);
    } else {
        int i = (bid - 5120) * 256 + tid;   // 65536 = 2048*32
        int t = i >> 5, d = i & 31;
        float inv_ts = exp2f(-0.41524101186092036f * (float)d);
        float ang = (float)t * inv_ts;
        tab[i] = make_float2(sinf(ang), cosf(ang));
    }
}

// ---------------- Fused QKV GEMM: 8-wave 128x128, counted-vmcnt 2-phase ----
// 512 threads: wave w owns 64(M) x 32(N): wy = w>>2, wx = w&3; acc[4][2].
// Same 64 KB double-buffered LDS and sync skeleton as the 4-wave version,
// but 16 waves/CU resident (was 8) for latency hiding.
// Epilogues rebuilt for 8 waves: q/k bounce fp32+bias via XOR-swizzled
// [128][128] f32 LDS (RoPE pairs span waves), then u16 bounce + coalesced
// store; v path re-indexed for 512 threads.
// q scale folds log2(e): scale_q = 0.125 * 1.4426950408889634
__global__ __launch_bounds__(512) void gemm_qkv(
    const unsigned short* __restrict__ A,    // [4096][1024]
    const unsigned short* __restrict__ BT,   // [3072][1024]
    const float* __restrict__ bias,          // [3072]
    const float2* __restrict__ tab,          // [2048][32]
    unsigned short* __restrict__ qT,
    unsigned short* __restrict__ kT,
    unsigned short* __restrict__ vT) {
    __shared__ __align__(16) unsigned short smem[32768];  // 2 x (as|bs), 64 KB
    int tid = threadIdx.x;
    int lane = tid & 63;
    int w = tid >> 6;                         // 0..7
    int wx = w & 3, wy = w >> 2;
    int l16 = lane & 15, quad = lane >> 4;
    // XCD-chunked swizzle: 768 blocks, 96/XCD as 8 m-panels x 12 n-tiles
    int lin = blockIdx.x;
    int xcd = lin & 7, idx = lin >> 3;        // idx 0..95
    int mb = (xcd >> 1) * 8 + idx / 12;       // 0..31
    int nb = (xcd & 1) * 12 + idx % 12;       // 0..23
    int m0 = mb * 128;
    int n0 = nb * 128;
    int x = l16 & 7;
    int lr = lane >> 3;
    int gc = (lane & 7) ^ lr;

    floatx4 acc[4][2];
#pragma unroll
    for (int mi = 0; mi < 4; mi++)
#pragma unroll
        for (int ni = 0; ni < 2; ni++)
            acc[mi][ni] = (floatx4){0.f, 0.f, 0.f, 0.f};

    auto stage = [&](int bsel, int k0) {
        unsigned short* as = smem + bsel * 16384;
        unsigned short* bs = as + 8192;
#pragma unroll
        for (int i = 0; i < 2; i++) {
            int seg = w * 2 + i;              // 0..15
            int row = seg * 8 + lr;
            gld16(A + (size_t)(m0 + row) * 1024 + k0 + gc * 8, &as[seg * 512]);
            gld16(BT + (size_t)(n0 + row) * 1024 + k0 + gc * 8, &bs[seg * 512]);
        }
    };

    auto compute = [&](int bsel) {
        const unsigned short* as = smem + bsel * 16384;
        const unsigned short* bs = as + 8192;
#pragma unroll
        for (int kk = 0; kk < 2; kk++) {
            short8 af[4], bf[2];
#pragma unroll
            for (int mi = 0; mi < 4; mi++) {
                int r = wy * 64 + mi * 16 + l16;
                af[mi] = *(const short8*)&as[r * 64 + (((kk << 2) | quad) ^ x) * 8];
            }
#pragma unroll
            for (int ni = 0; ni < 2; ni++) {
                int r = wx * 32 + ni * 16 + l16;
                bf[ni] = *(const short8*)&bs[r * 64 + (((kk << 2) | quad) ^ x) * 8];
            }
#pragma unroll
            for (int mi = 0; mi < 4; mi++)
#pragma unroll
                for (int ni = 0; ni < 2; ni++)
                    acc[mi][ni] = __builtin_amdgcn_mfma_f32_16x16x32_bf16(
                        af[mi], bf[ni], acc[mi][ni], 0, 0, 0);
        }
    };

    stage(0, 0);                 // loads(0) in flight
    int cur = 0;
    for (int k0 = 0; k0 < 960; k0 += 64) {
        stage(cur ^ 1, k0 + 64);                       // loads(t+1): 4/thread
        asm volatile("s_waitcnt vmcnt(4)" ::: "memory");  // loads(t) done
        __builtin_amdgcn_s_barrier();
        compute(cur);                                  // loads(t+1) still fly
        asm volatile("s_waitcnt lgkmcnt(0)" ::: "memory"); // my buf reads done
        __builtin_amdgcn_s_barrier();                  // all reads done
        cur ^= 1;
    }
    asm volatile("s_waitcnt vmcnt(0)" ::: "memory");
    __builtin_amdgcn_s_barrier();
    compute(cur);            // tail tile (k0 = 960)
    __syncthreads();         // all frag reads done before LDS reuse below

    int region = n0 >> 10;                    // 0=q, 1=k, 2=v
    int b = m0 >> 11;                         // tile never crosses batch
    float b0 = bias[n0 + wx * 32 + l16];
    float b1 = bias[n0 + wx * 32 + 16 + l16];

    if (region < 2) {
        // ---- q/k: fp32+bias -> swizzled LDS -> RoPE -> u16 bounce -> store
        unsigned short* qk = region ? kT : qT;
        float scale = region ? 1.0f : 0.18033688011112042f;  // 0.125*log2(e)
        float* F = (float*)smem;              // [128][128] f32, col^((row&7)<<2)
        // phase 1: write acc+bias (fp32)
#pragma unroll
        for (int mi = 0; mi < 4; mi++)
#pragma unroll
            for (int ni = 0; ni < 2; ni++) {
                float bv = ni ? b1 : b0;
                int col = wx * 32 + ni * 16 + l16;
#pragma unroll
                for (int r = 0; r < 4; r++) {
                    int row = wy * 64 + mi * 16 + quad * 4 + r;
                    F[row * 128 + (col ^ ((row & 7) << 2))] = acc[mi][ni][r] + bv;
                }
            }
        __syncthreads();
        // phase 2: RoPE in registers. thread -> (row tl, head hl, pairs d0..d0+15)
        int tl = tid >> 2, qq = tid & 3;
        int hl = qq >> 1, d0 = (qq & 1) * 16;
        int t = (m0 & 2047) + tl;
        int xr = (tl & 7) << 2;
        unsigned int lo[8], hi[8];
#pragma unroll
        for (int j = 0; j < 8; j++) {
            float o1[2], o2[2];
#pragma unroll
            for (int e = 0; e < 2; e++) {
                int d = d0 + j * 2 + e;
                float v1 = F[tl * 128 + ((hl * 64 + d) ^ xr)];
                float v2 = F[tl * 128 + ((hl * 64 + d + 32) ^ xr)];
                float2 sc = tab[t * 32 + d];
                o1[e] = (v1 * sc.y - v2 * sc.x) * scale;
                o2[e] = (v2 * sc.y + v1 * sc.x) * scale;
            }
            lo[j] = (unsigned int)f2bf(o1[0]) | ((unsigned int)f2bf(o1[1]) << 16);
            hi[j] = (unsigned int)f2bf(o2[0]) | ((unsigned int)f2bf(o2[1]) << 16);
        }
        __syncthreads();
        // phase 3: bf16 bounce tile [128][136]
        unsigned short* lq = smem;
        int base = tl * 136 + hl * 64 + d0;
#pragma unroll
        for (int j = 0; j < 4; j++) {
            *(uint2*)&lq[base + 4 * j] = make_uint2(lo[2 * j], lo[2 * j + 1]);
            *(uint2*)&lq[base + 32 + 4 * j] = make_uint2(hi[2 * j], hi[2 * j + 1]);
        }
        __syncthreads();
        // phase 4: coalesced store (8 threads per 128B head-row)
        int c8 = tid & 7;
        int hl2 = (tid >> 3) & 1;
        int tl0 = tid >> 4;                   // 0..31
        int h = ((n0 & 1023) >> 6) + hl2;
        unsigned short* ob = qk + (size_t)(b * 16 + h) * 2048 * 64;
#pragma unroll
        for (int p = 0; p < 4; p++) {
            int tl_ = p * 32 + tl0;
            int tt = (m0 & 2047) + tl_;
            short8 val = *(const short8*)&lq[tl_ * 136 + hl2 * 64 + c8 * 8];
            *(short8*)&ob[(size_t)tt * 64 + c8 * 8] = val;
        }
    } else {
        // ---- v: transpose 128x128 via LDS, write [bh][d][t] 16B runs ----
#pragma unroll
        for (int mi = 0; mi < 4; mi++)
#pragma unroll
            for (int ni = 0; ni < 2; ni++) {
                int d_loc = wx * 32 + ni * 16 + l16;
                int t_base = wy * 64 + mi * 16 + quad * 4;
                float bv = ni ? b1 : b0;
                uint2 pk;
                pk.x = pk2bf(acc[mi][ni][0] + bv, acc[mi][ni][1] + bv);
                pk.y = pk2bf(acc[mi][ni][2] + bv, acc[mi][ni][3] + bv);
                int e = d_loc * 128 + (t_base ^ ((d_loc & 15) << 3));
                *(uint2*)&smem[e] = pk;
            }
        __syncthreads();
        int d_r = tid >> 2, qtr = tid & 3;
        int cv = (n0 - 2048) + d_r;
        int hh = cv >> 6, dd = cv & 63;
        int fofs = (d_r & 15) << 3;
        size_t vbase = ((size_t)(b * 16 + hh) * 64 + dd) * 2048 + (m0 & 2047);
#pragma unroll
        for (int c = 0; c < 4; c++) {
            int tc = qtr * 32 + c * 8;
            short8 val = *(const short8*)&smem[d_r * 128 + (tc ^ fofs)];
            *(short8*)&vT[vbase + tc] = val;
        }
    }
}

// ---------------- proj GEMM: counted-vmcnt 2-phase + XCD swizzle -----------
__global__ __launch_bounds__(256) void gemm_proj(
    const unsigned short* __restrict__ A,    // y_bf [4096][1024]
    const unsigned short* __restrict__ BT,   // wTp [1024][1024]
    const float* __restrict__ bias,
    float* __restrict__ out) {
    __shared__ __align__(16) unsigned short smem[24576];  // 2 x (as|bs), 48 KB
    int lane = threadIdx.x & 63;
    int w = threadIdx.x >> 6;
    int wx = w & 1, wy = w >> 1;             // wave tile 64(M) x 32(N)
    int l16 = lane & 15, quad = lane >> 4;
    // XCD-chunked swizzle: 512 blocks, 64/XCD = 4 m-panels x 16 n (3MB/L2)
    int lin = blockIdx.x;
    int swz = (lin & 7) * 64 + (lin >> 3);
    int m0 = (swz >> 4) * 128;
    int n0 = (swz & 15) * 64;
    int x = l16 & 7;
    int lr = lane >> 3;
    int gc = (lane & 7) ^ lr;

    floatx4 acc[4][2];
#pragma unroll
    for (int mi = 0; mi < 4; mi++)
#pragma unroll
        for (int ni = 0; ni < 2; ni++)
            acc[mi][ni] = (floatx4){0.f, 0.f, 0.f, 0.f};

    auto stage = [&](int bsel, int k0) {
        unsigned short* as = smem + bsel * 12288;
        unsigned short* bs = as + 8192;
#pragma unroll
        for (int i = 0; i < 6; i++) {
            int seg = w * 6 + i;              // 24 segments: 16 A + 8 B
            if (seg < 16) {
                int row = seg * 8 + lr;
                gld16(A + (size_t)(m0 + row) * 1024 + k0 + gc * 8, &as[seg * 512]);
            } else {
                int s2 = seg - 16;
                int row = s2 * 8 + lr;
                gld16(BT + (size_t)(n0 + row) * 1024 + k0 + gc * 8, &bs[s2 * 512]);
            }
        }
    };

    auto compute = [&](int bsel) {
        const unsigned short* as = smem + bsel * 12288;
        const unsigned short* bs = as + 8192;
#pragma unroll
        for (int kk = 0; kk < 2; kk++) {
            short8 af[4], bf[2];
#pragma unroll
            for (int mi = 0; mi < 4; mi++) {
                int r = wy * 64 + mi * 16 + l16;
                af[mi] = *(const short8*)&as[r * 64 + (((kk << 2) | quad) ^ x) * 8];
            }
#pragma unroll
            for (int ni = 0; ni < 2; ni++) {
                int r = wx * 32 + ni * 16 + l16;
                bf[ni] = *(const short8*)&bs[r * 64 + (((kk << 2) | quad) ^ x) * 8];
            }
#pragma unroll
            for (int mi = 0; mi < 4; mi++)
#pragma unroll
                for (int ni = 0; ni < 2; ni++)
                    acc[mi][ni] = __builtin_amdgcn_mfma_f32_16x16x32_bf16(
                        af[mi], bf[ni], acc[mi][ni], 0, 0, 0);
        }
    };

    stage(0, 0);
    int cur = 0;
    for (int k0 = 0; k0 < 960; k0 += 64) {
        stage(cur ^ 1, k0 + 64);                       // loads(t+1): 6 vmem
        asm volatile("s_waitcnt vmcnt(6)" ::: "memory");  // loads(t) done
        __builtin_amdgcn_s_barrier();
        compute(cur);
        asm volatile("s_waitcnt lgkmcnt(0)" ::: "memory");
        __builtin_amdgcn_s_barrier();
        cur ^= 1;
    }
    asm volatile("s_waitcnt vmcnt(0)" ::: "memory");
    __builtin_amdgcn_s_barrier();
    compute(cur);

#pragma unroll
    for (int mi = 0; mi < 4; mi++)
#pragma unroll
        for (int ni = 0; ni < 2; ni++) {
            int row = m0 + wy * 64 + mi * 16 + quad * 4;
            int col = n0 + wx * 32 + ni * 16 + l16;
            float bv = bias[col];
#pragma unroll
            for (int r = 0; r < 4; r++)
                out[(size_t)(row + r) * 1024 + col] = acc[mi][ni][r] + bv;
        }
}

// ---------------- Flash attention v5 + counted-vmcnt (R5 block mapping) ----
__global__ __launch_bounds__(256) void attn5(
    const unsigned short* __restrict__ qT,
    const unsigned short* __restrict__ kT,
    const unsigned short* __restrict__ vT,
    unsigned short* __restrict__ y) {
    __shared__ __align__(16) unsigned short kbuf[2][64 * 64];
    __shared__ __align__(16) unsigned short vbuf[2][64 * 64];
    __shared__ __align__(16) unsigned short pl[4][16 * 72];
    int lane = threadIdx.x & 63;
    int w = threadIdx.x >> 6;                  // 0..3
    int l16 = lane & 15, quad = lane >> 4;
    int blk = blockIdx.x;                      // 0..1023
    int t = 31 - (blk >> 5);                   // q-tile, longest (t=31) first
    int bh = blk & 31;
    int b = bh >> 4, h = bh & 15;
    int q0 = t * 64 + w * 16;
    const unsigned short* qp = qT + (size_t)bh * 2048 * 64;
    unsigned short* plw = pl[w];
    int x = l16 & 7;

    short8 qf0 = *(const short8*)(qp + (size_t)(q0 + l16) * 64 + quad * 8);
    short8 qf1 = *(const short8*)(qp + (size_t)(q0 + l16) * 64 + 32 + quad * 8);

    short8 ones;
#pragma unroll
    for (int j = 0; j < 8; j++) ones[j] = (short)0x3F80;   // bf16 1.0

    floatx4 acc[4];
#pragma unroll
    for (int ni = 0; ni < 4; ni++) acc[ni] = (floatx4){0.f, 0.f, 0.f, 0.f};
    floatx4 accl = (floatx4){0.f, 0.f, 0.f, 0.f};

    // staging: waves 0,1 load K (8 segs), waves 2,3 load V (8 segs).
    int lr8 = lane >> 3, l8 = lane & 7;
    const unsigned short* sp[4];
    unsigned short* ld0[4];
    int gstep;
    if (w < 2) {
        const unsigned short* kp = kT + (size_t)bh * 2048 * 64;
#pragma unroll
        for (int i = 0; i < 4; i++) {
            int seg = w * 4 + i;
            int row = seg * 8 + lr8;
            int c = l8 ^ (row & 7);
            sp[i] = kp + (size_t)row * 64 + c * 8;
            ld0[i] = &kbuf[0][seg * 512];
        }
        gstep = 4096;                          // 64 rows * 64 u16
    } else {
        const unsigned short* vp = vT + (size_t)bh * 64 * 2048;
#pragma unroll
        for (int i = 0; i < 4; i++) {
            int s = (w - 2) * 4 + i;
            int d = s * 8 + lr8;
            int c = l8 ^ (d & 7);
            sp[i] = vp + (size_t)d * 2048 + c * 8;
            ld0[i] = &vbuf[0][s * 512];
        }
        gstep = 64;                            // advance 64 t per KV block
    }

    auto stage = [&](int bi) {
#pragma unroll
        for (int i = 0; i < 4; i++) {
            gld16(sp[i], ld0[i] + bi * 4096);
            sp[i] += gstep;
        }
    };

    int L = t + 1;
    int query = q0 + l16;
    stage(0);
    int cur = 0;
    for (int it = 0; it < L; it++) {
        if (it + 1 < L) {                      // block-uniform branch
            stage(cur ^ 1);                    // loads(t+1): 4 vmem in flight
            asm volatile("s_waitcnt vmcnt(4)" ::: "memory");  // loads(t) done
        } else {
            asm volatile("s_waitcnt vmcnt(0)" ::: "memory");
        }
        __builtin_amdgcn_s_barrier();
        const unsigned short* kb = kbuf[cur];
        const unsigned short* vb = vbuf[cur];
        bool diag = (it == t);                 // block-uniform
        floatx4 s4[4];
        __builtin_amdgcn_s_setprio(1);
#pragma unroll
        for (int c = 0; c < 4; c++) {
            int r = c * 16 + l16;
            short8 kf0 = *(const short8*)&kb[r * 64 + ((quad) ^ x) * 8];
            short8 kf1 = *(const short8*)&kb[r * 64 + ((quad | 4) ^ x) * 8];
            floatx4 z = (floatx4){0.f, 0.f, 0.f, 0.f};
            z = __builtin_amdgcn_mfma_f32_16x16x32_bf16(kf0, qf0, z, 0, 0, 0);
            z = __builtin_amdgcn_mfma_f32_16x16x32_bf16(kf1, qf1, z, 0, 0, 0);
            s4[c] = z;
        }
        __builtin_amdgcn_s_setprio(0);
        int j0 = it * 64;
#pragma unroll
        for (int c = 0; c < 4; c++) {
            float p[4];
#pragma unroll
            for (int r = 0; r < 4; r++) {
                float e = __builtin_amdgcn_exp2f(s4[c][r]);
                if (diag) {
                    int key = j0 + c * 16 + quad * 4 + r;
                    e = (key <= query) ? e : 0.f;
                }
                p[r] = e;
            }
            uint2 pk;
            pk.x = cvtpk(p[0], p[1]);
            pk.y = cvtpk(p[2], p[3]);
            *(uint2*)&plw[l16 * 72 + c * 16 + quad * 4] = pk;
        }
        short8 pa0 = *(const short8*)&plw[l16 * 72 + quad * 8];
        short8 pa1 = *(const short8*)&plw[l16 * 72 + 32 + quad * 8];
        __builtin_amdgcn_s_setprio(1);
        accl = __builtin_amdgcn_mfma_f32_16x16x32_bf16(pa0, ones, accl, 0, 0, 0);
        accl = __builtin_amdgcn_mfma_f32_16x16x32_bf16(pa1, ones, accl, 0, 0, 0);
#pragma unroll
        for (int ni = 0; ni < 4; ni++) {
            int d = ni * 16 + l16;
            short8 vf0 = *(const short8*)&vb[d * 64 + ((quad) ^ x) * 8];
            short8 vf1 = *(const short8*)&vb[d * 64 + ((quad | 4) ^ x) * 8];
            acc[ni] = __builtin_amdgcn_mfma_f32_16x16x32_bf16(pa0, vf0, acc[ni], 0, 0, 0);
            acc[ni] = __builtin_amdgcn_mfma_f32_16x16x32_bf16(pa1, vf1, acc[ni], 0, 0, 0);
        }
        __builtin_amdgcn_s_setprio(0);
        asm volatile("s_waitcnt lgkmcnt(0)" ::: "memory");  // buf reads done
        __builtin_amdgcn_s_barrier();          // safe to refill buf[cur]
        cur ^= 1;
    }

    float inv[4];
#pragma unroll
    for (int r = 0; r < 4; r++) inv[r] = 1.f / accl[r];
#pragma unroll
    for (int ni = 0; ni < 4; ni++)
#pragma unroll
        for (int r = 0; r < 4; r++) {
            int tr = q0 + quad * 4 + r;
            y[((size_t)(b * 2048 + tr)) * 1024 + h * 64 + ni * 16 + l16] =
                f2bf(acc[ni][r] * inv[r]);
        }
}

extern "C" void kernel_launch(void* const* d_in, const int* in_sizes, int n_in,
                              void* d_out, int out_size, void* d_ws, size_t ws_size,
                              hipStream_t stream) {
    const float* x      = (const float*)d_in[0];
    const float* w_attn = (const float*)d_in[1];
    const float* b_attn = (const float*)d_in[2];
    const float* w_proj = (const float*)d_in[3];
    const float* b_proj = (const float*)d_in[4];
    float* out = (float*)d_out;

    char* ws = (char*)d_ws;
    unsigned short* x_bf = (unsigned short*)ws;                    //  8 MB
    unsigned short* wTa  = (unsigned short*)(ws + (8ull << 20));   //  6 MB
    unsigned short* wTp  = (unsigned short*)(ws + (14ull << 20));  //  2 MB
    unsigned short* qTb  = (unsigned short*)(ws + (16ull << 20));  //  8 MB
    unsigned short* kTb  = (unsigned short*)(ws + (24ull << 20));  //  8 MB
    unsigned short* vTb  = (unsigned short*)(ws + (32ull << 20));  //  8 MB
    float2*         tab  = (float2*)(ws + (40ull << 20));          // 512 KB
    unsigned short* y_bf = x_bf;  // alias: x_bf dead after QKV GEMM

    prep<<<5376, 256, 0, stream>>>(x, w_attn, w_proj, x_bf, wTa, wTp, tab);
    gemm_qkv<<<768, 512, 0, stream>>>(x_bf, wTa, b_attn, tab, qTb, kTb, vTb);
    attn5<<<1024, 256, 0, stream>>>(qTb, kTb, vTb, y_bf);
    gemm_proj<<<512, 256, 0, stream>>>(y_bf, wTp, b_proj, out);
}